// Round 19
// baseline (508.750 us; speedup 1.0000x reference)
//
#include <hip/hip_runtime.h>
#include <math.h>

// Bahdanau attention, round 18: producer/consumer kernel split.
// k_cvtenc pre-converts enc fp32->bf16 into ws IN MFMA A-FRAGMENT ORDER
// (256 MiB). k_energy's K-loop is then pure: 8 coalesced 16B global loads
// (A from L3-resident abuf, B from L2-resident W2t) -> 16 MFMA. No LDS, no
// cvt, no barriers in-loop; ~110 regs -> 4 waves/SIMD (launch_bounds 256,4)
// -- the high-TLP regime no prior variant reached.
//   ws: dp (128K) | W2t (512K) | eparts/pctx (2M) | abuf (256M)

#define BATCH 64
#define SEQ   4096
#define HID   512

typedef __attribute__((ext_vector_type(8))) short bf16x8;
typedef __attribute__((ext_vector_type(4))) float f32x4;

__device__ __forceinline__ float fast_tanh(float x) {
    return 1.0f - 2.0f / (__expf(2.0f * x) + 1.0f);
}

__device__ __forceinline__ unsigned cvt2(float lo, float hi) {
    unsigned r;
    asm("v_cvt_pk_bf16_f32 %0, %1, %2" : "=v"(r) : "v"(lo), "v"(hi));
    return r;
}

// ---------------------------------------------------------------------------
// K0: W2 fp32 -> bf16 in MFMA fragment order:
//   u16 index = kb*16384 + wn*2048 + fn*512 + (rgl*16+gl)*8
// holds W2[g][k], g = wn*64 + fn*16 + gl, k = kb*32 + rgl*8 + j.
// ---------------------------------------------------------------------------
__global__ void k_cvtW2(const float* __restrict__ W2, ushort* __restrict__ W2t)
{
    const int n  = blockIdx.x * 256 + threadIdx.x;   // 0..32767
    const int g  = n >> 6, kc = n & 63;
    const int kb = kc >> 2, rgl = kc & 3;
    const int wn = g >> 6, fn = (g >> 4) & 3, gl = g & 15;

    const float* src = W2 + (size_t)g * HID + kc * 8;
    const float4 x = *reinterpret_cast<const float4*>(src);
    const float4 y = *reinterpret_cast<const float4*>(src + 4);
    uint4 u;
    u.x = cvt2(x.x, x.y);  u.y = cvt2(x.z, x.w);
    u.z = cvt2(y.x, y.y);  u.w = cvt2(y.z, y.w);

    const size_t dst = (size_t)kb * 16384 + wn * 2048 + fn * 512
                     + (rgl * 16 + gl) * 8;
    *reinterpret_cast<uint4*>(W2t + dst) = u;
}

// ---------------------------------------------------------------------------
// K0b: enc fp32 -> bf16 in MFMA A-fragment order.
// u16 fragment index n (8 u16 per thread):
//   l = n&63, m = (n>>6)&3, kb = (n>>8)&15, b = (n>>12)&63, c = n>>18
// holds enc[s][b][k] with s = c*64 + m*16 + (l&15), k = kb*32 + (l>>4)*8 + j.
// Reads: wave = 16 rows x 128B contiguous (full cache lines).
// Writes: 1KB contiguous per wave.
// ---------------------------------------------------------------------------
__global__ void k_cvtenc(const float* __restrict__ enc, ushort* __restrict__ abuf)
{
    const int n  = blockIdx.x * 256 + threadIdx.x;   // 0..16777215
    const int l  = n & 63;
    const int m  = (n >> 6) & 3;
    const int kb = (n >> 8) & 15;
    const int b  = (n >> 12) & 63;
    const int c  = n >> 18;

    const int s  = c * 64 + m * 16 + (l & 15);
    const int k0 = kb * 32 + (l >> 4) * 8;
    const float* src = enc + ((size_t)s * BATCH + b) * HID + k0;
    const float4 x = *reinterpret_cast<const float4*>(src);
    const float4 y = *reinterpret_cast<const float4*>(src + 4);
    uint4 u;
    u.x = cvt2(x.x, x.y);  u.y = cvt2(x.z, x.w);
    u.z = cvt2(y.x, y.y);  u.w = cvt2(y.z, y.w);
    *reinterpret_cast<uint4*>(abuf + (size_t)n * 8) = u;
}

// ---------------------------------------------------------------------------
// K1: dp[b][g] = sum_h dh[b][h] * W1[g][h]  (fp32, tiny)
// ---------------------------------------------------------------------------
__global__ void k_decproj(const float* __restrict__ dh,
                          const float* __restrict__ W1,
                          float* __restrict__ dp)
{
    __shared__ float wrow[HID];
    const int g = blockIdx.x;
    const int t = threadIdx.x;
    for (int i = t; i < HID; i += 256) wrow[i] = W1[g * HID + i];
    __syncthreads();

    const int b = t >> 2, q = t & 3;
    const float* dhb = dh + b * HID + q * 128;
    const float* wr  = wrow + q * 128;
    float acc = 0.f;
    #pragma unroll 8
    for (int i = 0; i < 128; i += 4) {
        const float4 d4 = *reinterpret_cast<const float4*>(dhb + i);
        acc = fmaf(d4.x, wr[i + 0], acc);
        acc = fmaf(d4.y, wr[i + 1], acc);
        acc = fmaf(d4.z, wr[i + 2], acc);
        acc = fmaf(d4.w, wr[i + 3], acc);
    }
    acc += __shfl_xor(acc, 1);
    acc += __shfl_xor(acc, 2);
    if (q == 0) dp[b * HID + g] = acc;
}

// ---------------------------------------------------------------------------
// K2: energy partial GEMM -- pure load->MFMA loop.
// grid = 8192 (R4 decode: gh siblings 8 apart -> same XCD shares abuf reads),
// 256 thr (4 waves). Block tile 64s x 256g; wave wv owns g [gh*256+wv*64,+64).
// Per step kb: af[m] = 16B at abase + kb*4096 + m*1024 (L3-resident abuf);
//              bfr[n] = 16B at bbase + kb*32768 + n*1024 (L2-resident W2t);
//              16 MFMA. No LDS/barriers until the 1KB epilogue reduction.
// ---------------------------------------------------------------------------
__global__ __launch_bounds__(256, 4)
void k_energy(const ushort* __restrict__ abuf, const ushort* __restrict__ W2t,
              const float* __restrict__ dp,  const float* __restrict__ v,
              float* __restrict__ eparts)
{
    __shared__ float part[4][64];

    const int idx  = blockIdx.x;
    const int g16  = idx >> 4, rr = idx & 15;
    const int gh   = rr >> 3;
    const int pair = (g16 << 3) | (rr & 7);    // 0..4095
    const int schunk = pair & 63;
    const int b      = pair >> 6;
    const int s0     = schunk * 64;

    const int t    = threadIdx.x;
    const int lane = t & 63;
    const int wv   = t >> 6;                   // wave 0..3 -> 64g slice
    const int gl   = lane & 15, rg = lane >> 4;

    f32x4 acc[4][4];
    const f32x4 z = {0.f, 0.f, 0.f, 0.f};
    #pragma unroll
    for (int m = 0; m < 4; ++m)
        #pragma unroll
        for (int n = 0; n < 4; ++n) acc[m][n] = z;

    // A: abuf bytes = (schunk*64+b)*65536 + kb*4096 + m*1024 + lane*16
    const char* abase = reinterpret_cast<const char*>(abuf)
                      + (size_t)(schunk * 64 + b) * 65536 + lane * 16;
    // B: W2t bytes = kb*32768 + gh*16384 + wv*4096 + n*1024 + lane*16
    const char* bbase = reinterpret_cast<const char*>(W2t)
                      + gh * 16384 + wv * 4096 + lane * 16;

    #pragma unroll
    for (int kb = 0; kb < 16; ++kb) {
        bf16x8 af[4], bfr[4];
        const char* astep = abase + kb * 4096;
        const char* bstep = bbase + kb * 32768;
        #pragma unroll
        for (int m = 0; m < 4; ++m)
            af[m] = *reinterpret_cast<const bf16x8*>(astep + m * 1024);
        #pragma unroll
        for (int n = 0; n < 4; ++n)
            bfr[n] = *reinterpret_cast<const bf16x8*>(bstep + n * 1024);

        #pragma unroll
        for (int m = 0; m < 4; ++m)
            #pragma unroll
            for (int n = 0; n < 4; ++n)
                acc[m][n] = __builtin_amdgcn_mfma_f32_16x16x32_bf16(
                    af[m], bfr[n], acc[m][n], 0, 0, 0);
    }

    // epilogue: partial energy over this block's 256 g
    float dpv[4], vv[4];
    #pragma unroll
    for (int n = 0; n < 4; ++n) {
        const int g = gh * 256 + wv * 64 + n * 16 + gl;
        dpv[n] = dp[b * HID + g];
        vv[n]  = v[g];
    }
    float p[4][4];
    #pragma unroll
    for (int m = 0; m < 4; ++m)
        #pragma unroll
        for (int r = 0; r < 4; ++r) p[m][r] = 0.f;
    #pragma unroll
    for (int n = 0; n < 4; ++n)
        #pragma unroll
        for (int m = 0; m < 4; ++m)
            #pragma unroll
            for (int r = 0; r < 4; ++r)
                p[m][r] += fast_tanh(dpv[n] + acc[m][n][r]) * vv[n];

    #pragma unroll
    for (int m = 0; m < 4; ++m)
        #pragma unroll
        for (int r = 0; r < 4; ++r) {
            float x = p[m][r];
            x += __shfl_xor(x, 1);
            x += __shfl_xor(x, 2);
            x += __shfl_xor(x, 4);
            x += __shfl_xor(x, 8);
            p[m][r] = x;
        }
    if (gl == 0) {
        #pragma unroll
        for (int m = 0; m < 4; ++m)
            #pragma unroll
            for (int r = 0; r < 4; ++r)
                part[wv][m * 16 + rg * 4 + r] = p[m][r];
    }
    __syncthreads();

    if (t < 64) {
        const float e = part[0][t] + part[1][t] + part[2][t] + part[3][t];
        eparts[(size_t)gh * BATCH * SEQ + (size_t)b * SEQ + s0 + t] = e;
    }
}

// ---------------------------------------------------------------------------
// K3: softmax over s per b; sums the two g-half partials, writes attn.
// ---------------------------------------------------------------------------
__global__ void k_softmax(const float* __restrict__ eparts,
                          float* __restrict__ attn)
{
    __shared__ float redm[4], reds[4];
    const int b = blockIdx.x, t = threadIdx.x;
    const float* e0 = eparts + (size_t)b * SEQ;
    const float* e1 = eparts + (size_t)BATCH * SEQ + (size_t)b * SEQ;

    float4 ev[4];
    float m = -3.4e38f;
    #pragma unroll
    for (int i = 0; i < 4; ++i) {
        const float4 x = *reinterpret_cast<const float4*>(e0 + i * 1024 + t * 4);
        const float4 y = *reinterpret_cast<const float4*>(e1 + i * 1024 + t * 4);
        ev[i] = make_float4(x.x + y.x, x.y + y.y, x.z + y.z, x.w + y.w);
        m = fmaxf(m, fmaxf(fmaxf(ev[i].x, ev[i].y), fmaxf(ev[i].z, ev[i].w)));
    }
    #pragma unroll
    for (int off = 1; off < 64; off <<= 1) m = fmaxf(m, __shfl_xor(m, off));
    if ((t & 63) == 0) redm[t >> 6] = m;
    __syncthreads();
    m = fmaxf(fmaxf(redm[0], redm[1]), fmaxf(redm[2], redm[3]));

    float s = 0.f;
    #pragma unroll
    for (int i = 0; i < 4; ++i) {
        ev[i].x = __expf(ev[i].x - m);  ev[i].y = __expf(ev[i].y - m);
        ev[i].z = __expf(ev[i].z - m);  ev[i].w = __expf(ev[i].w - m);
        s += (ev[i].x + ev[i].y) + (ev[i].z + ev[i].w);
    }
    #pragma unroll
    for (int off = 1; off < 64; off <<= 1) s += __shfl_xor(s, off);
    if ((t & 63) == 0) reds[t >> 6] = s;
    __syncthreads();
    s = (reds[0] + reds[1]) + (reds[2] + reds[3]);
    const float inv = 1.0f / s;

    float* o = attn + (size_t)b * SEQ;
    #pragma unroll
    for (int i = 0; i < 4; ++i) {
        const float4 w4 = make_float4(ev[i].x * inv, ev[i].y * inv,
                                      ev[i].z * inv, ev[i].w * inv);
        *reinterpret_cast<float4*>(o + i * 1024 + t * 4) = w4;
    }
}

// ---------------------------------------------------------------------------
// K4: partial context. grid = (64 b, 16 s-splits), 256 threads.
// ---------------------------------------------------------------------------
__global__ void k_ctxpart(const float* __restrict__ enc,
                          const float* __restrict__ attn,
                          float* __restrict__ pctx)
{
    __shared__ float w[256];
    const int b  = blockIdx.x;
    const int sp = blockIdx.y;
    const int t  = threadIdx.x;

    w[t] = attn[(size_t)b * SEQ + sp * 256 + t];
    __syncthreads();

    const float2* e2 = reinterpret_cast<const float2*>(enc);
    size_t idx = ((size_t)sp * 256 * BATCH + b) * (HID / 2) + t;
    const size_t stride = (size_t)BATCH * (HID / 2);

    float ax = 0.f, ay = 0.f;
    #pragma unroll 4
    for (int s = 0; s < 256; ++s) {
        const float2 ev = e2[idx];
        const float ws = w[s];
        ax = fmaf(ws, ev.x, ax);
        ay = fmaf(ws, ev.y, ay);
        idx += stride;
    }
    float2* p2 = reinterpret_cast<float2*>(pctx);
    p2[((size_t)sp * BATCH + b) * (HID / 2) + t] = make_float2(ax, ay);
}

// ---------------------------------------------------------------------------
// K5: context[b][h] = sum over 16 splits.
// ---------------------------------------------------------------------------
__global__ void k_ctxsum(const float* __restrict__ pctx,
                         float* __restrict__ ctx)
{
    const int i = blockIdx.x * 256 + threadIdx.x;
    float s = 0.f;
    #pragma unroll
    for (int sp = 0; sp < 16; ++sp) s += pctx[(size_t)sp * BATCH * HID + i];
    ctx[i] = s;
}

// ---------------------------------------------------------------------------
extern "C" void kernel_launch(void* const* d_in, const int* in_sizes, int n_in,
                              void* d_out, int out_size, void* d_ws, size_t ws_size,
                              hipStream_t stream)
{
    const float* dh  = (const float*)d_in[0];
    const float* enc = (const float*)d_in[1];
    const float* W1  = (const float*)d_in[2];
    const float* W2  = (const float*)d_in[3];
    const float* v   = (const float*)d_in[4];

    float* out  = (float*)d_out;
    float* ctx  = out;                           // 64*512
    float* attn = out + BATCH * HID;             // 64*4096

    float*  dp      = (float*)d_ws;                  // 128 KiB
    ushort* W2t     = (ushort*)(dp + BATCH * HID);   // 512 KiB (fragment order)
    float*  shared2 = (float*)(W2t + HID * HID);     // 2 MiB:
    float*  eparts  = shared2;                       //   [2][B][S] until softmax
    float*  pctx    = shared2;                       //   [16][B][H] after
    ushort* abuf    = (ushort*)(shared2 + 524288);   // 256 MiB (A-fragment order)

    k_cvtW2  <<<128, 256, 0, stream>>>(W2, W2t);
    k_cvtenc <<<65536, 256, 0, stream>>>(enc, abuf);
    k_decproj<<<HID, 256, 0, stream>>>(dh, W1, dp);
    k_energy <<<8192, 256, 0, stream>>>(abuf, W2t, dp, v, eparts);
    k_softmax<<<BATCH, 256, 0, stream>>>(eparts, attn);
    k_ctxpart<<<dim3(BATCH, 16), 256, 0, stream>>>(enc, attn, pctx);
    k_ctxsum <<<BATCH * HID / 256, 256, 0, stream>>>(pctx, ctx);
}

// Round 20
// 421.273 us; speedup vs baseline: 1.2076x; 1.2076x over previous
//
#include <hip/hip_runtime.h>
#include <math.h>

// Bahdanau attention, round 19: k-slice-pipelined energy kernel.
// R12's layout with the A-conversion folded INTO the K-loop: step kb
// converts/writes LDS slice kb+2 while MFMA consumes slice kb (af, bfr, and
// the fp32 A-rows are register ping-pongs issued 1-2 steps ahead). Each LDS
// location is written once per block -> no WAR hazard; RAW covered by ONE
// lgkm-only barrier per step with a full step of slack. The 512MB enc
// stream now overlaps MFMA instead of serializing before it (R12's
// phase-1/phase-2 split was the residual serial term).
//   ws: dp | W2t (fragment order) | pctx = 2.625 MiB

#define BATCH 64
#define SEQ   4096
#define HID   512

typedef __attribute__((ext_vector_type(8))) short bf16x8;
typedef __attribute__((ext_vector_type(4))) float f32x4;

__device__ __forceinline__ float fast_tanh(float x) {
    return 1.0f - 2.0f / (__expf(2.0f * x) + 1.0f);
}

__device__ __forceinline__ unsigned cvt2(float lo, float hi) {
    unsigned r;
    asm("v_cvt_pk_bf16_f32 %0, %1, %2" : "=v"(r) : "v"(lo), "v"(hi));
    return r;
}

// ---------------------------------------------------------------------------
// K0: W2 fp32 -> bf16 in MFMA fragment order:
//   u16 index = kb*16384 + wn*2048 + fn*512 + (rgl*16+gl)*8
// holds W2[g][k], g = wn*64 + fn*16 + gl, k = kb*32 + rgl*8 + j.
// ---------------------------------------------------------------------------
__global__ void k_cvtW2(const float* __restrict__ W2, ushort* __restrict__ W2t)
{
    const int n  = blockIdx.x * 256 + threadIdx.x;   // 0..32767
    const int g  = n >> 6, kc = n & 63;
    const int kb = kc >> 2, rgl = kc & 3;
    const int wn = g >> 6, fn = (g >> 4) & 3, gl = g & 15;

    const float* src = W2 + (size_t)g * HID + kc * 8;
    const float4 x = *reinterpret_cast<const float4*>(src);
    const float4 y = *reinterpret_cast<const float4*>(src + 4);
    uint4 u;
    u.x = cvt2(x.x, x.y);  u.y = cvt2(x.z, x.w);
    u.z = cvt2(y.x, y.y);  u.w = cvt2(y.z, y.w);

    const size_t dst = (size_t)kb * 16384 + wn * 2048 + fn * 512
                     + (rgl * 16 + gl) * 8;
    *reinterpret_cast<uint4*>(W2t + dst) = u;
}

// ---------------------------------------------------------------------------
// K1: dp[b][g] = sum_h dh[b][h] * W1[g][h]  (fp32, tiny)
// ---------------------------------------------------------------------------
__global__ void k_decproj(const float* __restrict__ dh,
                          const float* __restrict__ W1,
                          float* __restrict__ dp)
{
    __shared__ float wrow[HID];
    const int g = blockIdx.x;
    const int t = threadIdx.x;
    for (int i = t; i < HID; i += 256) wrow[i] = W1[g * HID + i];
    __syncthreads();

    const int b = t >> 2, q = t & 3;
    const float* dhb = dh + b * HID + q * 128;
    const float* wr  = wrow + q * 128;
    float acc = 0.f;
    #pragma unroll 8
    for (int i = 0; i < 128; i += 4) {
        const float4 d4 = *reinterpret_cast<const float4*>(dhb + i);
        acc = fmaf(d4.x, wr[i + 0], acc);
        acc = fmaf(d4.y, wr[i + 1], acc);
        acc = fmaf(d4.z, wr[i + 2], acc);
        acc = fmaf(d4.w, wr[i + 3], acc);
    }
    acc += __shfl_xor(acc, 1);
    acc += __shfl_xor(acc, 2);
    if (q == 0) dp[b * HID + g] = acc;
}

// ---------------------------------------------------------------------------
// K2: energy GEMM, k-slice pipelined. grid = 4096 (schunk=idx&63, b=idx>>6),
// 512 thr (8 waves). Wave w owns g [w*64, +64); block tile 64s x 512g.
// LDS: As row*1024B + (l^(row&7))*16B holds enc row, k=l*8..l*8+7 (R12 map).
// Slice sl <-> l in {4sl..4sl+3}. Staging threads: srow=t>>3, qh=(t&7)>>1,
// half=t&1 -> 16B fp32 load, cvt_pk, 8B ds_write per slice.
// Step kb: cvt+write slice kb+2 | refill A-regs slice kb+4 | bfr(kb+1) |
//          af(kb+1) | MFMA(kb) | lgkm(0)+s_barrier.
// ---------------------------------------------------------------------------
__global__ __launch_bounds__(512, 2)
void k_energy(const float* __restrict__ enc, const ushort* __restrict__ W2t,
              const float* __restrict__ dp,  const float* __restrict__ v,
              float* __restrict__ energy)
{
    __shared__ __align__(16) ushort As[64 * 512];      // 64 KiB
    __shared__ float part[8][64];                      //  2 KiB

    const int idx    = blockIdx.x;
    const int schunk = idx & 63;
    const int b      = idx >> 6;
    const int s0     = schunk * 64;

    const int t    = threadIdx.x;
    const int lane = t & 63;
    const int w    = t >> 6;                   // wave 0..7 -> g block
    const int gl   = lane & 15, rg = lane >> 4;

    // staging mapping
    const int srow = t >> 3;                   // 0..63
    const int qh   = (t & 7) >> 1;             // 0..3 lane-slot within slice
    const int half = t & 1;
    const float* aptr = enc + ((size_t)(s0 + srow) * BATCH + b) * HID
                      + qh * 8 + half * 4;     // + sl*32 per slice
    char* awbase = reinterpret_cast<char*>(As) + srow * 1024 + half * 8;
    const int rmask = srow & 7;

    f32x4 acc[4][4];
    const f32x4 z = {0.f, 0.f, 0.f, 0.f};
    #pragma unroll
    for (int m = 0; m < 4; ++m)
        #pragma unroll
        for (int n = 0; n < 4; ++n) acc[m][n] = z;

    const char* asbase = reinterpret_cast<const char*>(As) + gl * 1024;
    const char* bbase  = reinterpret_cast<const char*>(W2t)
                       + w * 4096 + lane * 16;
    const int   gmask  = gl & 7;

    bf16x8 af[2][4], bfr[2][4];
    float4 ar0, ar1;

    // ---- prologue: slices 0,1 staged; loads for 2,3 issued; bfr(0) ----
    {
        const float4 p0 = *reinterpret_cast<const float4*>(aptr);
        const float4 p1 = *reinterpret_cast<const float4*>(aptr + 32);
        uint2 u0, u1;
        u0.x = cvt2(p0.x, p0.y);  u0.y = cvt2(p0.z, p0.w);
        u1.x = cvt2(p1.x, p1.y);  u1.y = cvt2(p1.z, p1.w);
        *reinterpret_cast<uint2*>(awbase + ((qh)     ^ rmask) * 16) = u0;
        *reinterpret_cast<uint2*>(awbase + ((4 + qh) ^ rmask) * 16) = u1;
    }
    ar0 = *reinterpret_cast<const float4*>(aptr + 2 * 32);
    ar1 = *reinterpret_cast<const float4*>(aptr + 3 * 32);
    #pragma unroll
    for (int n = 0; n < 4; ++n)
        bfr[0][n] = *reinterpret_cast<const bf16x8*>(bbase + n * 1024);
    asm volatile("s_waitcnt lgkmcnt(0)" ::: "memory");
    __builtin_amdgcn_s_barrier();
    #pragma unroll
    for (int m = 0; m < 4; ++m)
        af[0][m] = *reinterpret_cast<const bf16x8*>(
            asbase + ((rg) ^ gmask) * 16 + m * 16384);

    // ---- main loop ----
    #pragma unroll
    for (int kb = 0; kb < 16; ++kb) {
        const int cur = kb & 1, nxt = cur ^ 1;

        // (a) cvt + ds_write slice kb+2 from A-regs (2-step flight)
        if (kb <= 13) {
            const float4 p = cur ? ar1 : ar0;
            uint2 u;
            u.x = cvt2(p.x, p.y);  u.y = cvt2(p.z, p.w);
            *reinterpret_cast<uint2*>(
                awbase + (((kb + 2) * 4 + qh) ^ rmask) * 16) = u;
        }
        // (b) refill A-regs with slice kb+4 (consumed at step kb+2)
        if (kb <= 11) {
            if (cur) ar1 = *reinterpret_cast<const float4*>(aptr + (kb + 4) * 32);
            else     ar0 = *reinterpret_cast<const float4*>(aptr + (kb + 4) * 32);
        }
        // (c) bfr(kb+1): 1-step L2 flight
        if (kb <= 14) {
            const char* bstep = bbase + (kb + 1) * 32768;
            #pragma unroll
            for (int n = 0; n < 4; ++n)
                bfr[nxt][n] = *reinterpret_cast<const bf16x8*>(bstep + n * 1024);
        }
        // (d) af(kb+1): slice kb+1 visible since barrier kb-1; 1-step flight
        if (kb <= 14) {
            const char* arow = asbase + ((4 * (kb + 1) + rg) ^ gmask) * 16;
            #pragma unroll
            for (int m = 0; m < 4; ++m)
                af[nxt][m] = *reinterpret_cast<const bf16x8*>(arow + m * 16384);
        }

        // (e) MFMA on step kb (inputs ready since last step)
        #pragma unroll
        for (int m = 0; m < 4; ++m)
            #pragma unroll
            for (int n = 0; n < 4; ++n)
                acc[m][n] = __builtin_amdgcn_mfma_f32_16x16x32_bf16(
                    af[cur][m], bfr[cur][n], acc[m][n], 0, 0, 0);

        // (f) one lgkm-only barrier: publishes slice kb+2, drains af reads
        asm volatile("s_waitcnt lgkmcnt(0)" ::: "memory");
        __builtin_amdgcn_s_barrier();
    }

    // ---- epilogue: energy over this block's full 512 g ----
    float dpv[4], vv[4];
    #pragma unroll
    for (int n = 0; n < 4; ++n) {
        const int g = w * 64 + n * 16 + gl;
        dpv[n] = dp[b * HID + g];
        vv[n]  = v[g];
    }
    float p[4][4];
    #pragma unroll
    for (int m = 0; m < 4; ++m)
        #pragma unroll
        for (int r = 0; r < 4; ++r) p[m][r] = 0.f;
    #pragma unroll
    for (int n = 0; n < 4; ++n)
        #pragma unroll
        for (int m = 0; m < 4; ++m)
            #pragma unroll
            for (int r = 0; r < 4; ++r)
                p[m][r] += fast_tanh(dpv[n] + acc[m][n][r]) * vv[n];

    #pragma unroll
    for (int m = 0; m < 4; ++m)
        #pragma unroll
        for (int r = 0; r < 4; ++r) {
            float x = p[m][r];
            x += __shfl_xor(x, 1);
            x += __shfl_xor(x, 2);
            x += __shfl_xor(x, 4);
            x += __shfl_xor(x, 8);
            p[m][r] = x;
        }
    if (gl == 0) {
        #pragma unroll
        for (int m = 0; m < 4; ++m)
            #pragma unroll
            for (int r = 0; r < 4; ++r)
                part[w][m * 16 + rg * 4 + r] = p[m][r];
    }
    __syncthreads();

    if (t < 64) {
        float e = 0.f;
        #pragma unroll
        for (int q2 = 0; q2 < 8; ++q2) e += part[q2][t];
        energy[(size_t)b * SEQ + s0 + t] = e;
    }
}

// ---------------------------------------------------------------------------
// K3: softmax over s per b, IN PLACE on the attn region of d_out.
// ---------------------------------------------------------------------------
__global__ void k_softmax(float* __restrict__ attn)
{
    __shared__ float redm[4], reds[4];
    const int b = blockIdx.x, t = threadIdx.x;
    float* e = attn + (size_t)b * SEQ;

    float4 ev[4];
    float m = -3.4e38f;
    #pragma unroll
    for (int i = 0; i < 4; ++i) {
        ev[i] = *reinterpret_cast<const float4*>(e + i * 1024 + t * 4);
        m = fmaxf(m, fmaxf(fmaxf(ev[i].x, ev[i].y), fmaxf(ev[i].z, ev[i].w)));
    }
    #pragma unroll
    for (int off = 1; off < 64; off <<= 1) m = fmaxf(m, __shfl_xor(m, off));
    if ((t & 63) == 0) redm[t >> 6] = m;
    __syncthreads();
    m = fmaxf(fmaxf(redm[0], redm[1]), fmaxf(redm[2], redm[3]));

    float s = 0.f;
    #pragma unroll
    for (int i = 0; i < 4; ++i) {
        ev[i].x = __expf(ev[i].x - m);  ev[i].y = __expf(ev[i].y - m);
        ev[i].z = __expf(ev[i].z - m);  ev[i].w = __expf(ev[i].w - m);
        s += (ev[i].x + ev[i].y) + (ev[i].z + ev[i].w);
    }
    #pragma unroll
    for (int off = 1; off < 64; off <<= 1) s += __shfl_xor(s, off);
    if ((t & 63) == 0) reds[t >> 6] = s;
    __syncthreads();
    s = (reds[0] + reds[1]) + (reds[2] + reds[3]);
    const float inv = 1.0f / s;

    #pragma unroll
    for (int i = 0; i < 4; ++i) {
        const float4 w4 = make_float4(ev[i].x * inv, ev[i].y * inv,
                                      ev[i].z * inv, ev[i].w * inv);
        *reinterpret_cast<float4*>(e + i * 1024 + t * 4) = w4;
    }
}

// ---------------------------------------------------------------------------
// K4: partial context. grid = (64 b, 16 s-splits), 256 threads.
// ---------------------------------------------------------------------------
__global__ void k_ctxpart(const float* __restrict__ enc,
                          const float* __restrict__ attn,
                          float* __restrict__ pctx)
{
    __shared__ float w[256];
    const int b  = blockIdx.x;
    const int sp = blockIdx.y;
    const int t  = threadIdx.x;

    w[t] = attn[(size_t)b * SEQ + sp * 256 + t];
    __syncthreads();

    const float2* e2 = reinterpret_cast<const float2*>(enc);
    size_t idx = ((size_t)sp * 256 * BATCH + b) * (HID / 2) + t;
    const size_t stride = (size_t)BATCH * (HID / 2);

    float ax = 0.f, ay = 0.f;
    #pragma unroll 4
    for (int s = 0; s < 256; ++s) {
        const float2 ev = e2[idx];
        const float ws = w[s];
        ax = fmaf(ws, ev.x, ax);
        ay = fmaf(ws, ev.y, ay);
        idx += stride;
    }
    float2* p2 = reinterpret_cast<float2*>(pctx);
    p2[((size_t)sp * BATCH + b) * (HID / 2) + t] = make_float2(ax, ay);
}

// ---------------------------------------------------------------------------
// K5: context[b][h] = sum over 16 splits.
// ---------------------------------------------------------------------------
__global__ void k_ctxsum(const float* __restrict__ pctx,
                         float* __restrict__ ctx)
{
    const int i = blockIdx.x * 256 + threadIdx.x;
    float s = 0.f;
    #pragma unroll
    for (int sp = 0; sp < 16; ++sp) s += pctx[(size_t)sp * BATCH * HID + i];
    ctx[i] = s;
}

// ---------------------------------------------------------------------------
extern "C" void kernel_launch(void* const* d_in, const int* in_sizes, int n_in,
                              void* d_out, int out_size, void* d_ws, size_t ws_size,
                              hipStream_t stream)
{
    const float* dh  = (const float*)d_in[0];
    const float* enc = (const float*)d_in[1];
    const float* W1  = (const float*)d_in[2];
    const float* W2  = (const float*)d_in[3];
    const float* v   = (const float*)d_in[4];

    float* out  = (float*)d_out;
    float* ctx  = out;                           // 64*512
    float* attn = out + BATCH * HID;             // 64*4096 (energy -> softmax in place)

    float*  dp   = (float*)d_ws;                 // 128 KiB
    ushort* W2t  = (ushort*)(dp + BATCH * HID);  // 512 KiB (fragment order)
    float*  pctx = (float*)(W2t + HID * HID);    // 2 MiB

    k_cvtW2  <<<128, 256, 0, stream>>>(W2, W2t);
    k_decproj<<<HID, 256, 0, stream>>>(dh, W1, dp);
    k_energy <<<4096, 512, 0, stream>>>(enc, W2t, dp, v, attn);
    k_softmax<<<BATCH, 256, 0, stream>>>(attn);
    k_ctxpart<<<dim3(BATCH, 16), 256, 0, stream>>>(enc, attn, pctx);
    k_ctxsum <<<BATCH * HID / 256, 256, 0, stream>>>(pctx, ctx);
}

// Round 21
// 318.464 us; speedup vs baseline: 1.5975x; 1.3228x over previous
//
#include <hip/hip_runtime.h>
#include <math.h>

// Bahdanau attention, round 20: R12 + 2-blocks-per-CU register diet.
// R12 (best known, 318us) had ONE 8-wave block/CU: block phases serialize
// and successive blocks can't overlap either. launch_bounds(512,4) admits
// TWO co-resident blocks (16 waves/CU) -- after the first generation block
// slots recycle asynchronously, so one block's K-loop overlaps the other's
// enc conversion. Needs <=128 regs/wave (64 AGPR acc + <=64 VGPR): phase 1
// runs as two 4-round halves to halve the load-temporary peak.
//   ws: dp | W2t (fragment order) | pctx = 2.625 MiB

#define BATCH 64
#define SEQ   4096
#define HID   512

typedef __attribute__((ext_vector_type(8))) short bf16x8;
typedef __attribute__((ext_vector_type(4))) float f32x4;

__device__ __forceinline__ float fast_tanh(float x) {
    return 1.0f - 2.0f / (__expf(2.0f * x) + 1.0f);
}

__device__ __forceinline__ unsigned cvt2(float lo, float hi) {
    unsigned r;
    asm("v_cvt_pk_bf16_f32 %0, %1, %2" : "=v"(r) : "v"(lo), "v"(hi));
    return r;
}

// ---------------------------------------------------------------------------
// K0: W2 fp32 -> bf16 in MFMA fragment order:
//   u16 index = kb*16384 + wn*2048 + fn*512 + (rgl*16+gl)*8
// holds W2[g][k], g = wn*64 + fn*16 + gl, k = kb*32 + rgl*8 + j.
// ---------------------------------------------------------------------------
__global__ void k_cvtW2(const float* __restrict__ W2, ushort* __restrict__ W2t)
{
    const int n  = blockIdx.x * 256 + threadIdx.x;   // 0..32767
    const int g  = n >> 6, kc = n & 63;
    const int kb = kc >> 2, rgl = kc & 3;
    const int wn = g >> 6, fn = (g >> 4) & 3, gl = g & 15;

    const float* src = W2 + (size_t)g * HID + kc * 8;
    const float4 x = *reinterpret_cast<const float4*>(src);
    const float4 y = *reinterpret_cast<const float4*>(src + 4);
    uint4 u;
    u.x = cvt2(x.x, x.y);  u.y = cvt2(x.z, x.w);
    u.z = cvt2(y.x, y.y);  u.w = cvt2(y.z, y.w);

    const size_t dst = (size_t)kb * 16384 + wn * 2048 + fn * 512
                     + (rgl * 16 + gl) * 8;
    *reinterpret_cast<uint4*>(W2t + dst) = u;
}

// ---------------------------------------------------------------------------
// K1: dp[b][g] = sum_h dh[b][h] * W1[g][h]  (fp32, tiny)
// ---------------------------------------------------------------------------
__global__ void k_decproj(const float* __restrict__ dh,
                          const float* __restrict__ W1,
                          float* __restrict__ dp)
{
    __shared__ float wrow[HID];
    const int g = blockIdx.x;
    const int t = threadIdx.x;
    for (int i = t; i < HID; i += 256) wrow[i] = W1[g * HID + i];
    __syncthreads();

    const int b = t >> 2, q = t & 3;
    const float* dhb = dh + b * HID + q * 128;
    const float* wr  = wrow + q * 128;
    float acc = 0.f;
    #pragma unroll 8
    for (int i = 0; i < 128; i += 4) {
        const float4 d4 = *reinterpret_cast<const float4*>(dhb + i);
        acc = fmaf(d4.x, wr[i + 0], acc);
        acc = fmaf(d4.y, wr[i + 1], acc);
        acc = fmaf(d4.z, wr[i + 2], acc);
        acc = fmaf(d4.w, wr[i + 3], acc);
    }
    acc += __shfl_xor(acc, 1);
    acc += __shfl_xor(acc, 2);
    if (q == 0) dp[b * HID + g] = acc;
}

// ---------------------------------------------------------------------------
// K2: energy GEMM, phase-split (R12) at 2 blocks/CU.
// grid = 4096 (schunk = idx&63, b = idx>>6), 512 thr (8 waves).
// Phase 1 (two 4-round halves): wave w converts rows {r*8+w}; lane l: 32B
//          load -> cvt_pk -> 16B ds_write at row*1024 + (l^(row&7))*16.
// Phase 2 (barrier-free): step kb: bfr 4x16B from W2t (L2), af 4x ds_read
//          from swizzled LDS, 16 MFMA.
// ---------------------------------------------------------------------------
__global__ __launch_bounds__(512, 4)
void k_energy(const float* __restrict__ enc, const ushort* __restrict__ W2t,
              const float* __restrict__ dp,  const float* __restrict__ v,
              float* __restrict__ energy)
{
    __shared__ __align__(16) ushort As[64 * 512];      // 64 KiB (swizzled)
    __shared__ float part[8][64];                      //  2 KiB

    const int idx    = blockIdx.x;
    const int schunk = idx & 63;
    const int b      = idx >> 6;
    const int s0     = schunk * 64;

    const int t    = threadIdx.x;
    const int lane = t & 63;
    const int w    = t >> 6;                   // wave 0..7 -> g block
    const int gl   = lane & 15, rg = lane >> 4;

    // ---- phase 1: convert enc slice into LDS (two halves: bounded regs) ----
    #pragma unroll
    for (int h = 0; h < 2; ++h) {
        #pragma unroll
        for (int r = 0; r < 4; ++r) {
            const int row = (h * 4 + r) * 8 + w;
            const float* rp = enc + ((size_t)(s0 + row) * BATCH + b) * HID + lane * 8;
            const float4 x = *reinterpret_cast<const float4*>(rp);
            const float4 y = *reinterpret_cast<const float4*>(rp + 4);
            uint4 u;
            u.x = cvt2(x.x, x.y);  u.y = cvt2(x.z, x.w);
            u.z = cvt2(y.x, y.y);  u.w = cvt2(y.z, y.w);
            const int slot = lane ^ (row & 7);
            *reinterpret_cast<uint4*>(
                reinterpret_cast<char*>(As) + row * 1024 + slot * 16) = u;
        }
    }
    __syncthreads();

    // ---- phase 2: barrier-free K-loop ----
    f32x4 acc[4][4];
    const f32x4 z = {0.f, 0.f, 0.f, 0.f};
    #pragma unroll
    for (int m = 0; m < 4; ++m)
        #pragma unroll
        for (int n = 0; n < 4; ++n) acc[m][n] = z;

    const char* asbase = reinterpret_cast<const char*>(As) + gl * 1024;
    const char* bbase  = reinterpret_cast<const char*>(W2t)
                       + w * 4096 + lane * 16;
    const int   gmask  = gl & 7;

    #pragma unroll
    for (int kb = 0; kb < 16; ++kb) {
        bf16x8 bfr[4];
        const char* bstep = bbase + kb * 32768;
        #pragma unroll
        for (int n = 0; n < 4; ++n)
            bfr[n] = *reinterpret_cast<const bf16x8*>(bstep + n * 1024);

        const char* arow = asbase + ((4 * kb + rg) ^ gmask) * 16;
        bf16x8 af[4];
        #pragma unroll
        for (int m = 0; m < 4; ++m)
            af[m] = *reinterpret_cast<const bf16x8*>(arow + m * 16384);

        #pragma unroll
        for (int m = 0; m < 4; ++m)
            #pragma unroll
            for (int n = 0; n < 4; ++n)
                acc[m][n] = __builtin_amdgcn_mfma_f32_16x16x32_bf16(
                    af[m], bfr[n], acc[m][n], 0, 0, 0);
    }

    // ---- epilogue: energy over this block's full 512 g ----
    float dpv[4], vv[4];
    #pragma unroll
    for (int n = 0; n < 4; ++n) {
        const int g = w * 64 + n * 16 + gl;
        dpv[n] = dp[b * HID + g];
        vv[n]  = v[g];
    }
    float p[4][4];
    #pragma unroll
    for (int m = 0; m < 4; ++m)
        #pragma unroll
        for (int r = 0; r < 4; ++r) p[m][r] = 0.f;
    #pragma unroll
    for (int n = 0; n < 4; ++n)
        #pragma unroll
        for (int m = 0; m < 4; ++m)
            #pragma unroll
            for (int r = 0; r < 4; ++r)
                p[m][r] += fast_tanh(dpv[n] + acc[m][n][r]) * vv[n];

    #pragma unroll
    for (int m = 0; m < 4; ++m)
        #pragma unroll
        for (int r = 0; r < 4; ++r) {
            float x = p[m][r];
            x += __shfl_xor(x, 1);
            x += __shfl_xor(x, 2);
            x += __shfl_xor(x, 4);
            x += __shfl_xor(x, 8);
            p[m][r] = x;
        }
    if (gl == 0) {
        #pragma unroll
        for (int m = 0; m < 4; ++m)
            #pragma unroll
            for (int r = 0; r < 4; ++r)
                part[w][m * 16 + rg * 4 + r] = p[m][r];
    }
    __syncthreads();

    if (t < 64) {
        float e = 0.f;
        #pragma unroll
        for (int q = 0; q < 8; ++q) e += part[q][t];
        energy[(size_t)b * SEQ + s0 + t] = e;
    }
}

// ---------------------------------------------------------------------------
// K3: softmax over s per b, IN PLACE on the attn region of d_out.
// ---------------------------------------------------------------------------
__global__ void k_softmax(float* __restrict__ attn)
{
    __shared__ float redm[4], reds[4];
    const int b = blockIdx.x, t = threadIdx.x;
    float* e = attn + (size_t)b * SEQ;

    float4 ev[4];
    float m = -3.4e38f;
    #pragma unroll
    for (int i = 0; i < 4; ++i) {
        ev[i] = *reinterpret_cast<const float4*>(e + i * 1024 + t * 4);
        m = fmaxf(m, fmaxf(fmaxf(ev[i].x, ev[i].y), fmaxf(ev[i].z, ev[i].w)));
    }
    #pragma unroll
    for (int off = 1; off < 64; off <<= 1) m = fmaxf(m, __shfl_xor(m, off));
    if ((t & 63) == 0) redm[t >> 6] = m;
    __syncthreads();
    m = fmaxf(fmaxf(redm[0], redm[1]), fmaxf(redm[2], redm[3]));

    float s = 0.f;
    #pragma unroll
    for (int i = 0; i < 4; ++i) {
        ev[i].x = __expf(ev[i].x - m);  ev[i].y = __expf(ev[i].y - m);
        ev[i].z = __expf(ev[i].z - m);  ev[i].w = __expf(ev[i].w - m);
        s += (ev[i].x + ev[i].y) + (ev[i].z + ev[i].w);
    }
    #pragma unroll
    for (int off = 1; off < 64; off <<= 1) s += __shfl_xor(s, off);
    if ((t & 63) == 0) reds[t >> 6] = s;
    __syncthreads();
    s = (reds[0] + reds[1]) + (reds[2] + reds[3]);
    const float inv = 1.0f / s;

    #pragma unroll
    for (int i = 0; i < 4; ++i) {
        const float4 w4 = make_float4(ev[i].x * inv, ev[i].y * inv,
                                      ev[i].z * inv, ev[i].w * inv);
        *reinterpret_cast<float4*>(e + i * 1024 + t * 4) = w4;
    }
}

// ---------------------------------------------------------------------------
// K4: partial context. grid = (64 b, 16 s-splits), 256 threads.
// ---------------------------------------------------------------------------
__global__ void k_ctxpart(const float* __restrict__ enc,
                          const float* __restrict__ attn,
                          float* __restrict__ pctx)
{
    __shared__ float w[256];
    const int b  = blockIdx.x;
    const int sp = blockIdx.y;
    const int t  = threadIdx.x;

    w[t] = attn[(size_t)b * SEQ + sp * 256 + t];
    __syncthreads();

    const float2* e2 = reinterpret_cast<const float2*>(enc);
    size_t idx = ((size_t)sp * 256 * BATCH + b) * (HID / 2) + t;
    const size_t stride = (size_t)BATCH * (HID / 2);

    float ax = 0.f, ay = 0.f;
    #pragma unroll 4
    for (int s = 0; s < 256; ++s) {
        const float2 ev = e2[idx];
        const float ws = w[s];
        ax = fmaf(ws, ev.x, ax);
        ay = fmaf(ws, ev.y, ay);
        idx += stride;
    }
    float2* p2 = reinterpret_cast<float2*>(pctx);
    p2[((size_t)sp * BATCH + b) * (HID / 2) + t] = make_float2(ax, ay);
}

// ---------------------------------------------------------------------------
// K5: context[b][h] = sum over 16 splits.
// ---------------------------------------------------------------------------
__global__ void k_ctxsum(const float* __restrict__ pctx,
                         float* __restrict__ ctx)
{
    const int i = blockIdx.x * 256 + threadIdx.x;
    float s = 0.f;
    #pragma unroll
    for (int sp = 0; sp < 16; ++sp) s += pctx[(size_t)sp * BATCH * HID + i];
    ctx[i] = s;
}

// ---------------------------------------------------------------------------
extern "C" void kernel_launch(void* const* d_in, const int* in_sizes, int n_in,
                              void* d_out, int out_size, void* d_ws, size_t ws_size,
                              hipStream_t stream)
{
    const float* dh  = (const float*)d_in[0];
    const float* enc = (const float*)d_in[1];
    const float* W1  = (const float*)d_in[2];
    const float* W2  = (const float*)d_in[3];
    const float* v   = (const float*)d_in[4];

    float* out  = (float*)d_out;
    float* ctx  = out;                           // 64*512
    float* attn = out + BATCH * HID;             // 64*4096 (energy -> softmax in place)

    float*  dp   = (float*)d_ws;                 // 128 KiB
    ushort* W2t  = (ushort*)(dp + BATCH * HID);  // 512 KiB (fragment order)
    float*  pctx = (float*)(W2t + HID * HID);    // 2 MiB

    k_cvtW2  <<<128, 256, 0, stream>>>(W2, W2t);
    k_decproj<<<HID, 256, 0, stream>>>(dh, W1, dp);
    k_energy <<<4096, 512, 0, stream>>>(enc, W2t, dp, v, attn);
    k_softmax<<<BATCH, 256, 0, stream>>>(attn);
    k_ctxpart<<<dim3(BATCH, 16), 256, 0, stream>>>(enc, attn, pctx);
    k_ctxsum <<<BATCH * HID / 256, 256, 0, stream>>>(pctx, ctx);
}